// Round 7
// baseline (234.130 us; speedup 1.0000x reference)
//
#include <hip/hip_runtime.h>
#include <hip/hip_bf16.h>
#include <math.h>

#define BB 64
#define NN 256
#define D_VIS 2048
#define D_LBL 512
#define HH 8
#define FF 256
#define DG 2048   // D_GAT = H*F
#define DE 512    // D_EMB
#define ALPHA 0.2f
#define PSTRIDE 264  // Pl row stride in shorts (256 + 8 pad)

using bf16 = __hip_bfloat16;
using short8 = __attribute__((ext_vector_type(8))) short;
using f32x4  = __attribute__((ext_vector_type(4))) float;
__device__ __forceinline__ float b2f(bf16 x) { return __bfloat162float(x); }
__device__ __forceinline__ unsigned short f2bs(float x) {
    bf16 h = __float2bfloat16(x);
    unsigned short u;
    __builtin_memcpy(&u, &h, 2);
    return u;
}

// ---------------- unified bf16-MFMA GEMM with fused epilogues.
// C[MxN] fp32 (+)= A[MxK] fp32 @ W[KxN] fp32 ; optional bf16-transposed store BT[n][m];
// optional per-row head dots: sOut[m*8+h] += sum_col acc*aSrc[col] (h = col>>8).
// grid (N/64, M/32, zsplit); block 256 (4 waves). Wave w owns cols n0+w*16..+16.
__global__ void __launch_bounds__(256) k_mgemm(const float* __restrict__ A, int lda,
                                               const float* __restrict__ W, int ldw,
                                               float* __restrict__ Cf32, int ldc,
                                               unsigned short* __restrict__ BT,
                                               const float* __restrict__ aSrc,
                                               const float* __restrict__ aDst,
                                               float* __restrict__ sOut,
                                               float* __restrict__ dOut,
                                               int kSlice, int kIters, int atomicC) {
    __shared__ unsigned short As[32][72]; // [m][k] bf16 bits
    __shared__ unsigned short Bs[64][72]; // [n][k] bf16 bits
    const int t = threadIdx.x;
    const int w = t >> 6;
    const int lane = t & 63;
    const int l15 = lane & 15, quad = lane >> 4;
    const int n0 = blockIdx.x * 64;
    const int m0 = blockIdx.y * 32;
    const int kb0 = blockIdx.z * kSlice;

    f32x4 acc[2];
    acc[0] = (f32x4){0.f, 0.f, 0.f, 0.f};
    acc[1] = (f32x4){0.f, 0.f, 0.f, 0.f};

    for (int kc = 0; kc < kIters; ++kc) {
        const int kb = kb0 + kc * 64;
#pragma unroll
        for (int p = 0; p < 2; ++p) {
            const int idx = t + 256 * p;
            const int r = idx >> 4, q4 = idx & 15;
            const float4 v = *(const float4*)(A + (size_t)(m0 + r) * lda + kb + 4 * q4);
            unsigned short s4[4] = {f2bs(v.x), f2bs(v.y), f2bs(v.z), f2bs(v.w)};
            __builtin_memcpy(&As[r][4 * q4], s4, 8);
        }
        {
            const int n = t & 63;
            float bv[16];
#pragma unroll
            for (int i = 0; i < 16; ++i)
                bv[i] = W[(size_t)(kb + w * 16 + i) * ldw + n0 + n];
            unsigned short s8[8];
#pragma unroll
            for (int i = 0; i < 8; ++i) s8[i] = f2bs(bv[i]);
            __builtin_memcpy(&Bs[n][w * 16], s8, 16);
#pragma unroll
            for (int i = 0; i < 8; ++i) s8[i] = f2bs(bv[8 + i]);
            __builtin_memcpy(&Bs[n][w * 16 + 8], s8, 16);
        }
        __syncthreads();
#pragma unroll
        for (int ks = 0; ks < 2; ++ks) {
            const short8 bf = *(const short8*)&Bs[w * 16 + l15][ks * 32 + quad * 8];
#pragma unroll
            for (int mi = 0; mi < 2; ++mi) {
                const short8 af = *(const short8*)&As[mi * 16 + l15][ks * 32 + quad * 8];
                acc[mi] = __builtin_amdgcn_mfma_f32_16x16x32_bf16(af, bf, acc[mi], 0, 0, 0);
            }
        }
        __syncthreads();
    }
    const int col = n0 + w * 16 + l15;
    if (Cf32) {
#pragma unroll
        for (int mi = 0; mi < 2; ++mi)
#pragma unroll
            for (int r = 0; r < 4; ++r) {
                const int row = m0 + mi * 16 + quad * 4 + r;
                if (atomicC) atomicAdd(&Cf32[(size_t)row * ldc + col], acc[mi][r]);
                else Cf32[(size_t)row * ldc + col] = acc[mi][r];
            }
    }
    if (BT) { // bf16 transposed store: BT[col][row]
#pragma unroll
        for (int mi = 0; mi < 2; ++mi) {
            unsigned short s4[4];
#pragma unroll
            for (int r = 0; r < 4; ++r) s4[r] = f2bs(acc[mi][r]);
            __builtin_memcpy(&BT[(size_t)col * NN + m0 + mi * 16 + quad * 4], s4, 8);
        }
    }
    if (sOut) { // head-projection partial dots over this block's 16-col slice
        const float as = aSrc[col];
        const float ad = aDst[col];
        const int h = n0 >> 8; // block fully inside one head (64 | 256)
#pragma unroll
        for (int mi = 0; mi < 2; ++mi)
#pragma unroll
            for (int r = 0; r < 4; ++r) {
                float sv = acc[mi][r] * as;
                float dv = acc[mi][r] * ad;
#pragma unroll
                for (int off = 1; off < 16; off <<= 1) {
                    sv += __shfl_xor(sv, off);
                    dv += __shfl_xor(dv, off);
                }
                if (l15 == 0) {
                    const int row = m0 + mi * 16 + quad * 4 + r;
                    atomicAdd(&sOut[row * HH + h], sv);
                    atomicAdd(&dOut[row * HH + h], dv);
                }
            }
    }
}

// ---------------- init out with bias (fc accumulates atomically into it)
__global__ void __launch_bounds__(256) k_bias(const float* __restrict__ fcb,
                                              float* __restrict__ out) {
    const int i = blockIdx.x * 256 + threadIdx.x;
    out[i] = fcb[i & (DE - 1)];
}

// ---------------- MFMA GAT, fused softmax + P@W + ELU + store + pool-score
// grid (b,h,it) = 64*8*4 blocks, 512 thr (8 waves). Block: rows i0..i0+63, head h.
__global__ void __launch_bounds__(512) k_gat(const unsigned short* __restrict__ WhLbT,
                                             const float* __restrict__ WhV,
                                             const float* __restrict__ srcL,
                                             const float* __restrict__ dstL,
                                             const float* __restrict__ srcV,
                                             const float* __restrict__ dstV,
                                             const float* __restrict__ adj,
                                             const float* __restrict__ pool_q,
                                             bf16* __restrict__ outb,
                                             float* __restrict__ ps) {
    const int bid = blockIdx.x;
    const int it = bid & 3;
    const int h  = (bid >> 2) & 7;
    const int b  = bid >> 5;
    const int i0 = it * 64;
    const int t = threadIdx.x;
    const int w = t >> 6;        // wave 0..7
    const int lane = t & 63;
    const int l15 = lane & 15, quad = lane >> 4;

    __shared__ __align__(16) unsigned short Pl[64][PSTRIDE]; // 33.8 KB
    __shared__ float dls[NN];
    __shared__ float sls[64];

    if (t < NN) dls[t] = dstL[t * HH + h];
    if (t < 64) sls[t] = srcL[(i0 + t) * HH + h];
    const float c = srcV[b * HH + h] + dstV[b * HH + h];
    __syncthreads();

    // ---- phase 1: masked softmax (no max-sub: |e| bounded). Wave w: rows w*8..+8.
    {
        const int g = lane >> 4, s = lane & 15;
        for (int rr = 0; rr < 2; ++rr) {
            const int iloc = w * 8 + rr * 4 + g;
            const int i = i0 + iloc;
            const float u = c + sls[iloc];
            float pr[16];
            float sum = 0.f;
#pragma unroll
            for (int jj = 0; jj < 8; ++jj) {
                const int j0 = 2 * s + 32 * jj;
                const float2 av = *(const float2*)(adj + (size_t)i * NN + j0);
                float x0 = u + dls[j0];
                float x1 = u + dls[j0 + 1];
                x0 = fmaxf(x0, ALPHA * x0);       // LeakyReLU
                x1 = fmaxf(x1, ALPHA * x1);
                const float p0 = av.x > 0.f ? __expf(x0) : 0.f;
                const float p1 = av.y > 0.f ? __expf(x1) : 0.f;
                pr[2 * jj] = p0; pr[2 * jj + 1] = p1;
                sum += p0 + p1;
            }
#pragma unroll
            for (int off = 1; off < 16; off <<= 1) sum += __shfl_xor(sum, off);
            const float inv = 1.0f / sum;
#pragma unroll
            for (int jj = 0; jj < 8; ++jj) {
                const unsigned int pk =
                    ((unsigned int)f2bs(pr[2 * jj + 1] * inv) << 16) |
                    f2bs(pr[2 * jj] * inv);
                *(unsigned int*)&Pl[iloc][2 * s + 32 * jj] = pk;
            }
        }
    }
    __syncthreads();

    // ---- phase 2: out[i0:+64, w*32:+32] = P @ WhL (mfma 16x16x32 bf16)
    const int n0 = w * 32;
    f32x4 acc[4][2];
#pragma unroll
    for (int mi = 0; mi < 4; ++mi)
#pragma unroll
        for (int ni = 0; ni < 2; ++ni) acc[mi][ni] = (f32x4){0.f, 0.f, 0.f, 0.f};

    const unsigned short* wb = WhLbT + (size_t)(h * FF + n0 + l15) * NN + quad * 8;
#pragma unroll 2
    for (int kc = 0; kc < 8; ++kc) {
        short8 a[4], bfr[2];
#pragma unroll
        for (int mi = 0; mi < 4; ++mi)
            a[mi] = *(const short8*)&Pl[mi * 16 + l15][kc * 32 + quad * 8];
#pragma unroll
        for (int ni = 0; ni < 2; ++ni)
            bfr[ni] = *(const short8*)(wb + (size_t)(ni * 16) * NN + kc * 32);
#pragma unroll
        for (int mi = 0; mi < 4; ++mi)
#pragma unroll
            for (int ni = 0; ni < 2; ++ni)
                acc[mi][ni] = __builtin_amdgcn_mfma_f32_16x16x32_bf16(
                    a[mi], bfr[ni], acc[mi][ni], 0, 0, 0);
    }
    __syncthreads(); // all waves done reading Pl

    // ---- epilogue A: +WhV, ELU, bf16 -> Pl[row][f]
    float wv[2];
#pragma unroll
    for (int ni = 0; ni < 2; ++ni)
        wv[ni] = WhV[(size_t)b * DG + h * FF + n0 + ni * 16 + l15];
#pragma unroll
    for (int mi = 0; mi < 4; ++mi)
#pragma unroll
        for (int ni = 0; ni < 2; ++ni)
#pragma unroll
            for (int r = 0; r < 4; ++r) {
                float x = acc[mi][ni][r] + wv[ni];
                x = x > 0.f ? x : (__expf(x) - 1.0f); // ELU
                Pl[mi * 16 + quad * 4 + r][n0 + ni * 16 + l15] = f2bs(x);
            }
    __syncthreads();

    // ---- epilogue B: coalesced b128 stores + fused pool-score partial dot
    {
        const int r = t >> 3;        // 0..63
        const int cb = t & 7;        // 0..7
        const int f0 = cb * 32;
        const float* pq = pool_q + h * FF + f0;
        bf16* orow = outb + ((size_t)(b * NN + i0 + r)) * DG + h * FF + f0;
        float dot = 0.f;
#pragma unroll
        for (int i8 = 0; i8 < 4; ++i8) {
            const short8 v = *(const short8*)&Pl[r][f0 + 8 * i8];
            __builtin_memcpy(orow + 8 * i8, &v, 16);
            const float4 q0 = *(const float4*)(pq + 8 * i8);
            const float4 q1 = *(const float4*)(pq + 8 * i8 + 4);
            bf16 bb[8];
            __builtin_memcpy(bb, &v, 16);
            dot = fmaf(b2f(bb[0]), q0.x, dot);
            dot = fmaf(b2f(bb[1]), q0.y, dot);
            dot = fmaf(b2f(bb[2]), q0.z, dot);
            dot = fmaf(b2f(bb[3]), q0.w, dot);
            dot = fmaf(b2f(bb[4]), q1.x, dot);
            dot = fmaf(b2f(bb[5]), q1.y, dot);
            dot = fmaf(b2f(bb[6]), q1.z, dot);
            dot = fmaf(b2f(bb[7]), q1.w, dot);
        }
        dot += __shfl_xor(dot, 1);
        dot += __shfl_xor(dot, 2);
        dot += __shfl_xor(dot, 4);
        if (cb == 0) atomicAdd(&ps[b * NN + i0 + r], dot);
    }
}

// ---------------- pooled[b,d] = sum_n softmax(ps)[n] * out[b,n,d]  (inline softmax)
__global__ void __launch_bounds__(256) k_pool(const bf16* __restrict__ outb,
                                              const float* __restrict__ ps,
                                              float* __restrict__ pooled) {
    const int dt = blockIdx.x;  // 0..7
    const int b  = blockIdx.y;  // 0..63
    const int t  = threadIdx.x;
    __shared__ float wsm[NN];
    __shared__ float redm[4];
    __shared__ float reds[4];
    const float v = ps[b * NN + t];
    float m = v;
#pragma unroll
    for (int off = 32; off; off >>= 1) m = fmaxf(m, __shfl_xor(m, off));
    if ((t & 63) == 0) redm[t >> 6] = m;
    __syncthreads();
    m = fmaxf(fmaxf(redm[0], redm[1]), fmaxf(redm[2], redm[3]));
    const float e = __expf(v - m);
    float s = e;
#pragma unroll
    for (int off = 32; off; off >>= 1) s += __shfl_xor(s, off);
    if ((t & 63) == 0) reds[t >> 6] = s;
    __syncthreads();
    s = reds[0] + reds[1] + reds[2] + reds[3];
    wsm[t] = e / s;
    __syncthreads();
    const int d = dt * 256 + t;
    float acc = 0.f;
    const bf16* base = outb + (size_t)b * NN * DG + d;
    for (int n = 0; n < NN; ++n)
        acc = fmaf(wsm[n], b2f(base[(size_t)n * DG]), acc);
    pooled[(size_t)b * DG + d] = acc;
}

extern "C" void kernel_launch(void* const* d_in, const int* in_sizes, int n_in,
                              void* d_out, int out_size, void* d_ws, size_t ws_size,
                              hipStream_t stream) {
    (void)in_sizes; (void)n_in; (void)out_size; (void)ws_size;
    const float* visual = (const float*)d_in[0];
    const float* labels = (const float*)d_in[1];
    const float* adj    = (const float*)d_in[2];
    const float* Wg     = (const float*)d_in[3];
    const float* a_src  = (const float*)d_in[4];
    const float* a_dst  = (const float*)d_in[5];
    const float* pool_q = (const float*)d_in[6];
    const float* fcW    = (const float*)d_in[7];
    const float* fcb    = (const float*)d_in[8];
    float* out = (float*)d_out;

    // workspace: [memset region: WhV srcL dstL srcV dstV ps] pooled outb WhLbT
    float* ws_f   = (float*)d_ws;
    float* WhV    = ws_f;                  // 64*2048
    float* srcL   = WhV + BB * DG;         // 256*8
    float* dstL   = srcL + NN * HH;        // 256*8
    float* srcV   = dstL + NN * HH;        // 64*8
    float* dstV   = srcV + BB * HH;        // 64*8
    float* ps     = dstV + BB * HH;        // 64*256
    float* pooled = ps + BB * NN;          // 64*2048
    bf16*  outb   = (bf16*)(pooled + BB * DG);        // 64*256*2048 bf16
    unsigned short* WhLbT = (unsigned short*)(outb + (size_t)BB * NN * DG); // 2048*256

    const size_t zero_floats = (size_t)BB * DG + NN * HH * 2 + BB * HH * 2 + BB * NN;
    hipMemsetAsync(WhV, 0, zero_floats * sizeof(float), stream);
    k_bias<<<BB * DE / 256, 256, 0, stream>>>(fcb, out);

    // WhL GEMM -> bf16 transposed WhLbT + srcL/dstL dots (no fp32 C)
    k_mgemm<<<dim3(DG / 64, NN / 32, 1), 256, 0, stream>>>(
        labels, D_LBL, Wg, DG, nullptr, 0, WhLbT, a_src, a_dst, srcL, dstL,
        D_LBL, D_LBL / 64, 0);
    // WhV GEMM -> fp32 WhV (atomic ksplit) + srcV/dstV dots
    k_mgemm<<<dim3(DG / 64, BB / 32, 4), 256, 0, stream>>>(
        visual, D_VIS, Wg + (size_t)D_LBL * DG, DG, WhV, DG, nullptr,
        a_src, a_dst, srcV, dstV, 512, 8, 1);

    k_gat<<<BB * HH * 4, 512, 0, stream>>>(WhLbT, WhV, srcL, dstL, srcV, dstV,
                                           adj, pool_q, outb, ps);

    k_pool<<<dim3(DG / 256, BB), 256, 0, stream>>>(outb, ps, pooled);

    // out = pooled @ fcW + bias: ksplit atomic into bias-init out
    k_mgemm<<<dim3(DE / 64, BB / 32, 8), 256, 0, stream>>>(
        pooled, DG, fcW, DE, out, DE, nullptr, nullptr, nullptr, nullptr, nullptr,
        256, 4, 1);
}